// Round 6
// baseline (197.228 us; speedup 1.0000x reference)
//
#include <hip/hip_runtime.h>
#include <hip/hip_cooperative_groups.h>

namespace cg = cooperative_groups;

#define NB 8
#define NT 1024
#define NE 128
#define NH 8
#define NS 16

// Workspace layout (floats). Each of Q/K/V/Y is B*H*T*S = B*T*E = 1048576 floats (4 MB).
#define WS_Q 0
#define WS_K 1048576
#define WS_V 2097152
#define WS_Y 3145728

#define WT_PITCH 132  // multiple of 4 -> every row 16B-aligned for float4 LDS reads

typedef float v2f __attribute__((ext_vector_type(2)));

static __device__ __forceinline__ v2f vlo(const float4 v) { return v2f{v.x, v.y}; }
static __device__ __forceinline__ v2f vhi(const float4 v) { return v2f{v.z, v.w}; }
static __device__ __forceinline__ v2f pfma(v2f a, v2f b, v2f c) {
  return __builtin_elementwise_fma(a, b, c);  // v_pk_fma_f32 on gfx950
}

// packed fma4: 2 v_pk_fma_f32 instead of 4 v_fma_f32 (round-3 proven transform)
static __device__ __forceinline__ void fma4(float4& acc, float s, const float4 v) {
  v2f lo = pfma(v2f{s, s}, vlo(v), vlo(acc));
  v2f hi = pfma(v2f{s, s}, vhi(v), vhi(acc));
  acc.x = lo.x; acc.y = lo.y; acc.z = hi.x; acc.w = hi.y;
}

// Packed-FP32 dot of two 16-float vectors: 8 v_pk_fma/mul + combine.
static __device__ __forceinline__ float dot16p(const float4 q0, const float4 q1,
                                               const float4 q2, const float4 q3,
                                               const float4 k0, const float4 k1,
                                               const float4 k2, const float4 k3) {
  v2f a = vlo(q0) * vlo(k0);
  v2f b = vhi(q0) * vhi(k0);
  a = pfma(vlo(q1), vlo(k1), a);
  b = pfma(vhi(q1), vhi(k1), b);
  a = pfma(vlo(q2), vlo(k2), a);
  b = pfma(vhi(q2), vhi(k2), b);
  a = pfma(vlo(q3), vlo(k3), a);
  b = pfma(vhi(q3), vhi(k3), b);
  v2f c = a + b;
  return c.x + c.y;
}

// ================== FUSED PIPELINE (cooperative, 1 dispatch) ==============
// Rounds 0-5 post-mortem: total - attn = ~78-84 us, CONSTANT across major
// code changes to qkv/proj, while both kernels' first-principles cost is
// <10 us each -> fixed per-launch / inter-kernel overhead, not instruction
// streams. Fuse all 3 kernels into one cooperative launch (grid = 256 blocks
// = 1/CU, co-resident by construction) with 2 grid.sync()s.
//   phase 1: qkv        (4 head-rowgroup units per block, round-3 body)
//   phase 2: attention  (round-5 structure; mask compaction per-block in LDS)
//   phase 3: projection (512-thread variant, 32 rows/block)
// One 50176 B LDS pool re-carved per phase:
//   phase 2: vidx[1024 ints] | Ks[128][16] | Vs[128][16]; epilogue om aliases
//            Ks/Vs ([8][64][20] = 40960 B at pool+1024)
//   phase 3: Wt[64*132] (33792 B) | Yt[32*128] (16384 B) = 50176 B
__global__ __launch_bounds__(512) void fused_kernel(
    const float* __restrict__ x, const int* __restrict__ masks,
    const float* __restrict__ Wq, const float* __restrict__ Wk,
    const float* __restrict__ Wv, const float* __restrict__ Wu,
    const float* __restrict__ bu, float* __restrict__ Qg,
    float* __restrict__ Kg, float* __restrict__ Vg, float* __restrict__ Yg,
    float* __restrict__ out) {
  __shared__ __align__(16) float pool[12544];  // 50176 B
  __shared__ int nv_s;
  const int tid = threadIdx.x;
  const int bid = blockIdx.x;
  cg::grid_group grid = cg::this_grid();

  // ---------------- phase 1: QKV projection --------------------------------
  // 1024 units of (64 rows x 1 head); 4 units/block: half = tid>>8 picks 2,
  // u2 loops 2. Within a unit: d = t&15, rows = (t>>4)*4 .. +3 (round-3 body).
  {
    const int t256 = tid & 255;
    const int half = tid >> 8;
    const int d = t256 & 15;
    const int rr = (t256 >> 4) << 2;
    const float4* wq4 = (const float4*)(Wq + d * 16);
    const float4 wq0 = wq4[0], wq1 = wq4[1], wq2 = wq4[2], wq3 = wq4[3];
    const float4* wk4 = (const float4*)(Wk + d * 16);
    const float4 wk0 = wk4[0], wk1 = wk4[1], wk2 = wk4[2], wk3 = wk4[3];
    const float4* wv4 = (const float4*)(Wv + d * 16);
    const float4 wv0 = wv4[0], wv1 = wv4[1], wv2 = wv4[2], wv3 = wv4[3];
    const float invs = 0.08838834764831845f;  // 1/sqrt(128)
#pragma unroll
    for (int u2 = 0; u2 < 2; u2++) {
      const int unit = (bid << 2) + (half << 1) + u2;
      const int h = unit & 7;
      const int rg = unit >> 3;   // 0..127 (global 64-row group)
      const int b = rg >> 4;
      const int base = rg << 6;   // global row base (b*NT + t)
#pragma unroll
      for (int i = 0; i < 4; i++) {
        const int row = base + rr + i;
        const float4* xp = (const float4*)(x + (size_t)row * 128 + h * 16);
        const float4 x0 = xp[0], x1 = xp[1], x2 = xp[2], x3 = xp[3];
        float aq = dot16p(x0, x1, x2, x3, wq0, wq1, wq2, wq3);
        float ak = dot16p(x0, x1, x2, x3, wk0, wk1, wk2, wk3);
        float av = dot16p(x0, x1, x2, x3, wv0, wv1, wv2, wv3);
        const int t = row & 1023;
        size_t o = ((size_t)(b * NH + h) * NT + t) * NS + d;
        Qg[o] = aq * invs;
        Kg[o] = ak;
        Vg[o] = av;
      }
    }
  }
  grid.sync();

  // ---------------- phase 2: attention (round-5 structure) -----------------
  {
    int* vidx_l = (int*)pool;        // [1024]
    float* Ks = pool + 1024;         // [128][16]
    float* Vs = pool + 3072;         // [128][16]
    const int lane = tid & 63;
    const int s = tid >> 6;          // key-split 0..7 (= wave id)
    const int bh = bid >> 2;
    const int b = bh >> 3, h = bh & 7;
    const int tbase = (bid & 3) << 8;  // 256-query tile

    // per-block mask compaction into LDS (reads only `masks` -> no cross-
    // block dependency; replaces the global vidx round-trip)
    if (tid < 64) {
      int basec = 0;
      for (int c = 0; c < NT; c += 64) {
        int t = c + tid;
        int v = masks[b * NT + t] != 0;
        unsigned long long bal = __ballot(v);
        int pos = basec + __popcll(bal & ((1ull << tid) - 1ull));
        if (v) vidx_l[pos] = t;
        basec += __popcll(bal);
      }
      if (tid == 0) nv_s = basec;
    }
    __syncthreads();
    const int nv = nv_s;

    // 4 queries per thread
    float4 q[4][4];
#pragma unroll
    for (int qq = 0; qq < 4; qq++) {
      const float4* qg =
          (const float4*)(Qg + ((size_t)bh * NT + tbase + (qq << 6) + lane) * NS);
      q[qq][0] = qg[0]; q[qq][1] = qg[1]; q[qq][2] = qg[2]; q[qq][3] = qg[3];
    }
    v2f o[4][8];
    float m[4], l[4];
#pragma unroll
    for (int qq = 0; qq < 4; qq++) {
      m[qq] = -1e30f; l[qq] = 0.f;
#pragma unroll
      for (int k = 0; k < 8; k++) o[qq][k] = v2f{0.f, 0.f};
    }

    for (int k0 = 0; k0 < nv; k0 += 128) {
      __syncthreads();
      {
        const int quad = tid & 3;
        const int jr = tid >> 2;  // 0..127
        int j = k0 + jr;
        float4 kv = {0, 0, 0, 0}, vv = {0, 0, 0, 0};
        if (j < nv) {
          int kk = vidx_l[j];
          size_t bse = ((size_t)bh * NT + kk) * NS + (quad << 2);
          kv = *(const float4*)(Kg + bse);
          vv = *(const float4*)(Vg + bse);
        }
        *(float4*)(Ks + jr * 16 + (quad << 2)) = kv;
        *(float4*)(Vs + jr * 16 + (quad << 2)) = vv;
      }
      __syncthreads();
      int jmax = nv - k0;
      if (jmax > 128) jmax = 128;
      for (int g = 0; g < 4; g++) {
        const int rb = s + (g << 5);
        if (rb >= jmax) break;  // wave-uniform
        float sc[4][4];
#pragma unroll
        for (int i = 0; i < 4; i++) {
          const float4* kr = (const float4*)(Ks + (rb + (i << 3)) * 16);
          const float4 k0v = kr[0], k1v = kr[1], k2v = kr[2], k3v = kr[3];
#pragma unroll
          for (int qq = 0; qq < 4; qq++)
            sc[qq][i] = dot16p(q[qq][0], q[qq][1], q[qq][2], q[qq][3], k0v, k1v,
                               k2v, k3v);
        }
#pragma unroll
        for (int i = 0; i < 4; i++)
          if (rb + (i << 3) >= jmax) {
            sc[0][i] = -1e30f; sc[1][i] = -1e30f;
            sc[2][i] = -1e30f; sc[3][i] = -1e30f;
          }
        float p[4][4];
#pragma unroll
        for (int qq = 0; qq < 4; qq++) {
          float mb =
              fmaxf(fmaxf(sc[qq][0], sc[qq][1]), fmaxf(sc[qq][2], sc[qq][3]));
          if (mb > m[qq]) {
            float al = __expf(m[qq] - mb);
            v2f al2 = {al, al};
            l[qq] *= al;
#pragma unroll
            for (int k = 0; k < 8; k++) o[qq][k] *= al2;
            m[qq] = mb;
          }
          p[qq][0] = __expf(sc[qq][0] - m[qq]);
          p[qq][1] = __expf(sc[qq][1] - m[qq]);
          p[qq][2] = __expf(sc[qq][2] - m[qq]);
          p[qq][3] = __expf(sc[qq][3] - m[qq]);
          l[qq] += (p[qq][0] + p[qq][1]) + (p[qq][2] + p[qq][3]);
        }
#pragma unroll
        for (int i = 0; i < 4; i++) {
          const float4* vr = (const float4*)(Vs + (rb + (i << 3)) * 16);
          const float4 v0 = vr[0], v1 = vr[1], v2 = vr[2], v3 = vr[3];
#pragma unroll
          for (int qq = 0; qq < 4; qq++) {
            const v2f pq = {p[qq][i], p[qq][i]};
            o[qq][0] = pfma(pq, vlo(v0), o[qq][0]);
            o[qq][1] = pfma(pq, vhi(v0), o[qq][1]);
            o[qq][2] = pfma(pq, vlo(v1), o[qq][2]);
            o[qq][3] = pfma(pq, vhi(v1), o[qq][3]);
            o[qq][4] = pfma(pq, vlo(v2), o[qq][4]);
            o[qq][5] = pfma(pq, vhi(v2), o[qq][5]);
            o[qq][6] = pfma(pq, vlo(v3), o[qq][6]);
            o[qq][7] = pfma(pq, vhi(v3), o[qq][7]);
          }
        }
      }
    }

    // epilogue: 4 phases, om ([8][64][20]) aliases Ks/Vs at pool+1024
    float* om = pool + 1024;
#pragma unroll
    for (int ph = 0; ph < 4; ph++) {
      __syncthreads();
      {
        float* pa = om + (s * 64 + lane) * 20;
#pragma unroll
        for (int k = 0; k < 8; k++) *(v2f*)(pa + k * 2) = o[ph][k];
        pa[16] = m[ph];
        pa[17] = l[ph];
      }
      __syncthreads();
      {
        const int q8 = tid >> 3;  // 0..63: query within slot
        const int sub = tid & 7;  // 0..7: which v2f of the 16-float output
        float ms[8], ls[8];
#pragma unroll
        for (int ss = 0; ss < 8; ss++) {
          const float* pp = om + (ss * 64 + q8) * 20;
          ms[ss] = pp[16];
          ls[ss] = pp[17];
        }
        float M = fmaxf(fmaxf(fmaxf(ms[0], ms[1]), fmaxf(ms[2], ms[3])),
                        fmaxf(fmaxf(ms[4], ms[5]), fmaxf(ms[6], ms[7])));
        float L = 0.f;
        v2f y = {0.f, 0.f};
#pragma unroll
        for (int ss = 0; ss < 8; ss++) {
          float f = __expf(ms[ss] - M);
          L = fmaf(f, ls[ss], L);
          v2f ov = *(const v2f*)(om + (ss * 64 + q8) * 20 + sub * 2);
          y = pfma(v2f{f, f}, ov, y);
        }
        const int tq = tbase + (ph << 6) + q8;
        const int qm = masks[b * NT + tq];
        const float inv = (qm != 0 && L > 0.f) ? (1.0f / L) : 0.f;
        y *= v2f{inv, inv};
        *(v2f*)(Yg + ((size_t)b * NT + tq) * NE + h * NS + sub * 2) = y;
      }
    }
  }
  grid.sync();

  // ---------------- phase 3: out = Y @ Wu^T + bu (32 rows/block) -----------
  {
    float* Wt = pool;         // [64 * WT_PITCH] = 8448 floats (33792 B)
    float* Yt = pool + 8448;  // [32 * 128] = 4096 floats (16384 B)
    const int r0 = bid * 32;
    const float4* yg = (const float4*)(Yg + (size_t)r0 * 128);
    float4* yt4 = (float4*)Yt;
    yt4[tid] = yg[tid];
    yt4[tid + 512] = yg[tid + 512];
    const int c0 = (tid & 31) << 2;
    const int rgp = (tid >> 5) & 7;  // 8 rowgroups x 4 rows = 32 rows
    const int eh = tid >> 8;         // 0 or 1 (e-half)
    float4 acc0 = {0, 0, 0, 0}, acc1 = {0, 0, 0, 0}, acc2 = {0, 0, 0, 0},
           acc3 = {0, 0, 0, 0};
    for (int e0 = 0; e0 < 128; e0 += 64) {
      __syncthreads();  // guards Yt staging (iter 0) and Wt reuse (iter 1)
#pragma unroll
      for (int p = 0; p < 4; p++) {
        int idx = tid + p * 512;
        int c = idx >> 4;
        int es = (idx & 15) << 2;
        float4 w = *(const float4*)(Wu + c * 128 + e0 + es);
        Wt[(es + 0) * WT_PITCH + c] = w.x;
        Wt[(es + 1) * WT_PITCH + c] = w.y;
        Wt[(es + 2) * WT_PITCH + c] = w.z;
        Wt[(es + 3) * WT_PITCH + c] = w.w;
      }
      __syncthreads();
      const int eb = eh << 5;
      const float* y0 = Yt + (rgp * 4 + 0) * 128 + e0 + eb;
      const float* y1 = Yt + (rgp * 4 + 1) * 128 + e0 + eb;
      const float* y2 = Yt + (rgp * 4 + 2) * 128 + e0 + eb;
      const float* y3 = Yt + (rgp * 4 + 3) * 128 + e0 + eb;
#pragma unroll 4
      for (int e = 0; e < 32; e += 4) {
        const float* wb = Wt + (eb + e) * WT_PITCH + c0;
        float4 w0 = *(const float4*)(wb + 0 * WT_PITCH);
        float4 w1 = *(const float4*)(wb + 1 * WT_PITCH);
        float4 w2 = *(const float4*)(wb + 2 * WT_PITCH);
        float4 w3 = *(const float4*)(wb + 3 * WT_PITCH);
        float4 ya = *(const float4*)(y0 + e);
        float4 yb = *(const float4*)(y1 + e);
        float4 yc = *(const float4*)(y2 + e);
        float4 yd = *(const float4*)(y3 + e);
        fma4(acc0, ya.x, w0); fma4(acc0, ya.y, w1); fma4(acc0, ya.z, w2); fma4(acc0, ya.w, w3);
        fma4(acc1, yb.x, w0); fma4(acc1, yb.y, w1); fma4(acc1, yb.z, w2); fma4(acc1, yb.w, w3);
        fma4(acc2, yc.x, w0); fma4(acc2, yc.y, w1); fma4(acc2, yc.z, w2); fma4(acc2, yc.w, w3);
        fma4(acc3, yd.x, w0); fma4(acc3, yd.y, w1); fma4(acc3, yd.z, w2); fma4(acc3, yd.w, w3);
      }
    }
    // combine e-halves through LDS (Wt dead; pitch 20 to spread banks)
    __syncthreads();
    if (eh == 1) {
      float* p = Wt + (tid & 255) * 20;
      *(float4*)(p + 0) = acc0; *(float4*)(p + 4) = acc1;
      *(float4*)(p + 8) = acc2; *(float4*)(p + 12) = acc3;
    }
    __syncthreads();
    if (eh == 0) {
      const float* p = Wt + tid * 20;
      float4 b4 = *(const float4*)(bu + c0);
      float4 q0 = *(const float4*)(p + 0);
      float4 q1 = *(const float4*)(p + 4);
      float4 q2 = *(const float4*)(p + 8);
      float4 q3 = *(const float4*)(p + 12);
      acc0.x += q0.x + b4.x; acc0.y += q0.y + b4.y; acc0.z += q0.z + b4.z; acc0.w += q0.w + b4.w;
      acc1.x += q1.x + b4.x; acc1.y += q1.y + b4.y; acc1.z += q1.z + b4.z; acc1.w += q1.w + b4.w;
      acc2.x += q2.x + b4.x; acc2.y += q2.y + b4.y; acc2.z += q2.z + b4.z; acc2.w += q2.w + b4.w;
      acc3.x += q3.x + b4.x; acc3.y += q3.y + b4.y; acc3.z += q3.z + b4.z; acc3.w += q3.w + b4.w;
      *(float4*)(out + (size_t)(r0 + rgp * 4 + 0) * 128 + c0) = acc0;
      *(float4*)(out + (size_t)(r0 + rgp * 4 + 1) * 128 + c0) = acc1;
      *(float4*)(out + (size_t)(r0 + rgp * 4 + 2) * 128 + c0) = acc2;
      *(float4*)(out + (size_t)(r0 + rgp * 4 + 3) * 128 + c0) = acc3;
    }
  }
}

extern "C" void kernel_launch(void* const* d_in, const int* in_sizes, int n_in,
                              void* d_out, int out_size, void* d_ws,
                              size_t ws_size, hipStream_t stream) {
  const float* x = (const float*)d_in[0];
  const int* masks = (const int*)d_in[1];
  const float* Wq = (const float*)d_in[2];
  const float* Wk = (const float*)d_in[3];
  const float* Wv = (const float*)d_in[4];
  const float* Wu = (const float*)d_in[5];
  const float* bu = (const float*)d_in[6];
  float* out = (float*)d_out;

  float* ws = (float*)d_ws;
  float* Q = ws + WS_Q;
  float* K = ws + WS_K;
  float* V = ws + WS_V;
  float* Y = ws + WS_Y;

  void* args[] = {&x, &masks, &Wq, &Wk, &Wv, &Wu, &bu,
                  &Q, &K, &V, &Y, &out};
  hipLaunchCooperativeKernel((const void*)fused_kernel, dim3(256), dim3(512),
                             args, 0, stream);
}

// Round 7
// 135.613 us; speedup vs baseline: 1.4543x; 1.4543x over previous
//
#include <hip/hip_runtime.h>

#define NB 8
#define NT 1024
#define NE 128
#define NH 8
#define NS 16

// Workspace layout (floats). Each of Q/K/V/Y is B*H*T*S = B*T*E = 1048576 floats (4 MB).
#define WS_Q 0
#define WS_K 1048576
#define WS_V 2097152
#define WS_Y 3145728
#define WS_VIDX 4194304

#define WT_PITCH 132  // multiple of 4 -> every row 16B-aligned for float4 LDS reads

typedef float v2f __attribute__((ext_vector_type(2)));

static __device__ __forceinline__ v2f vlo(const float4 v) { return v2f{v.x, v.y}; }
static __device__ __forceinline__ v2f vhi(const float4 v) { return v2f{v.z, v.w}; }
static __device__ __forceinline__ v2f pfma(v2f a, v2f b, v2f c) {
  return __builtin_elementwise_fma(a, b, c);  // v_pk_fma_f32 on gfx950
}

// packed fma4: 2 v_pk_fma_f32 instead of 4 v_fma_f32 (round-3 proven transform)
static __device__ __forceinline__ void fma4(float4& acc, float s, const float4 v) {
  v2f lo = pfma(v2f{s, s}, vlo(v), vlo(acc));
  v2f hi = pfma(v2f{s, s}, vhi(v), vhi(acc));
  acc.x = lo.x; acc.y = lo.y; acc.z = hi.x; acc.w = hi.y;
}

// Packed-FP32 dot of two 16-float vectors: 8 v_pk_fma/mul + combine.
static __device__ __forceinline__ float dot16p(const float4 q0, const float4 q1,
                                               const float4 q2, const float4 q3,
                                               const float4 k0, const float4 k1,
                                               const float4 k2, const float4 k3) {
  v2f a = vlo(q0) * vlo(k0);
  v2f b = vhi(q0) * vhi(k0);
  a = pfma(vlo(q1), vlo(k1), a);
  b = pfma(vhi(q1), vhi(k1), b);
  a = pfma(vlo(q2), vlo(k2), a);
  b = pfma(vhi(q2), vhi(k2), b);
  a = pfma(vlo(q3), vlo(k3), a);
  b = pfma(vhi(q3), vhi(k3), b);
  v2f c = a + b;
  return c.x + c.y;
}

// ---------------- Kernel A: fused QKV projection + mask compaction -------
// blocks [0,1024): qkv. block -> (h = blk&7, rowgroup = blk>>3 of 64 rows).
// x-slice [64 rows][16 floats] staged in LDS ONCE (1 coalesced float4/thread).
// blocks [1024,1032): per-batch mask compaction (wave 0 only).
__global__ __launch_bounds__(256) void qkv_kernel(
    const float* __restrict__ x, const int* __restrict__ masks,
    const float* __restrict__ Wq, const float* __restrict__ Wk,
    const float* __restrict__ Wv, float* __restrict__ Q, float* __restrict__ K,
    float* __restrict__ V, int* __restrict__ vidx, int* __restrict__ vcount) {
  if (blockIdx.x >= 1024) {
    const int b = blockIdx.x - 1024;
    const int lane = threadIdx.x;
    if (lane < 64) {
      int base = 0;
      for (int c = 0; c < NT; c += 64) {
        int t = c + lane;
        int v = masks[b * NT + t] != 0;
        unsigned long long bal = __ballot(v);
        int pos = base + __popcll(bal & ((1ull << lane) - 1ull));
        if (v) vidx[b * NT + pos] = t;
        base += __popcll(bal);
      }
      if (lane == 0) vcount[b] = base;
    }
    return;
  }
  __shared__ __align__(16) float xs[64 * 20];  // 5120 B, pitch 20
  const int tid = threadIdx.x;
  const int h = blockIdx.x & 7;
  const int rg = blockIdx.x >> 3;  // 0..127
  const int b = rg >> 4;
  const int base = rg << 6;  // global row base (b*NT + t)
  // stage: thread t -> row t>>2, quad t&3
  {
    const int sr = tid >> 2, sq = tid & 3;
    float4 xv = *(const float4*)(x + (size_t)(base + sr) * 128 + h * 16 + sq * 4);
    *(float4*)(xs + sr * 20 + sq * 4) = xv;
  }
  const int d = tid & 15;
  const int r = (tid >> 4) << 2;  // first of this thread's 4 rows (block-local)
  const float4* wq4 = (const float4*)(Wq + d * 16);
  const float4 wq0 = wq4[0], wq1 = wq4[1], wq2 = wq4[2], wq3 = wq4[3];
  const float4* wk4 = (const float4*)(Wk + d * 16);
  const float4 wk0 = wk4[0], wk1 = wk4[1], wk2 = wk4[2], wk3 = wk4[3];
  const float4* wv4 = (const float4*)(Wv + d * 16);
  const float4 wv0 = wv4[0], wv1 = wv4[1], wv2 = wv4[2], wv3 = wv4[3];
  const float invs = 0.08838834764831845f;  // 1/sqrt(128)
  __syncthreads();
#pragma unroll
  for (int i = 0; i < 4; i++) {
    const int row = r + i;
    const float4* xp = (const float4*)(xs + row * 20);
    const float4 x0 = xp[0], x1 = xp[1], x2 = xp[2], x3 = xp[3];
    float aq = dot16p(x0, x1, x2, x3, wq0, wq1, wq2, wq3);
    float ak = dot16p(x0, x1, x2, x3, wk0, wk1, wk2, wk3);
    float av = dot16p(x0, x1, x2, x3, wv0, wv1, wv2, wv3);
    const int t = (base + row) & 1023;
    size_t o = ((size_t)(b * NH + h) * NT + t) * NS + d;
    Q[o] = aq * invs;
    K[o] = ak;
    V[o] = av;
  }
}

// ---------------- Kernel B: QUERY-COMPACTED split-K attention -------------
// Round-6 post-mortem: the ~80 us "overhead" is harness-fixed (present even
// with one cooperative dispatch); qkv/proj are ~3 us each. Only lever left
// is attn device time. Half the queries are masked and their output is
// zeroed -> compact the QUERY axis with the same vidx list: work halves.
// Structure: r5 block body verbatim (256-query tiles, 512 thr, 8 key-splits,
// 4 q/thread = proven DS amortization), but tiles index COMPACTED queries.
// grid = 4 tiles x 64 bh, bid = tile*64 + bh (tile-major so the active-tile
// prefix spreads <=1 active block per CU; tiles with tbase >= nv exit).
// Q loads gather via vidx; epilogue scatters Y[vidx[cq]]. Masked Y rows are
// zeroed by proj (mask select at staging). DS floor per unit:
// 8 waves x 4 tiles x 16 rows x 8 ds_read_b128 = 4096 ~= 20 us.
__global__ __launch_bounds__(512) void attn_kernel(
    const float* __restrict__ Q, const float* __restrict__ K,
    const float* __restrict__ V, const int* __restrict__ vidx,
    const int* __restrict__ vcount, float* __restrict__ Y) {
  __shared__ __align__(16) float smem[10240];  // 40960 B
  float* Ks = smem;          // [128][16]
  float* Vs = smem + 2048;   // [128][16]
  const int tid = threadIdx.x;
  const int lane = tid & 63;
  const int s = tid >> 6;  // key-split 0..7 (= wave id)
  const int bh = blockIdx.x & 63;
  const int tile = blockIdx.x >> 6;  // 0..3 over COMPACTED queries
  const int b = bh >> 3, h = bh & 7;
  const int tbase = tile << 8;  // compacted-query tile base
  const int nv = vcount[b];
  if (tbase >= nv) return;  // inactive tile: whole block exits (~1 us)

  // 4 compacted queries per thread (gather rows via vidx; clamp for tails)
  float4 q[4][4];
#pragma unroll
  for (int qq = 0; qq < 4; qq++) {
    int cq = tbase + (qq << 6) + lane;
    int cqc = (cq < nv) ? cq : (nv - 1);
    int tq = vidx[b * NT + cqc];
    const float4* qg = (const float4*)(Q + ((size_t)bh * NT + tq) * NS);
    q[qq][0] = qg[0]; q[qq][1] = qg[1]; q[qq][2] = qg[2]; q[qq][3] = qg[3];
  }
  v2f o[4][8];
  float m[4], l[4];
#pragma unroll
  for (int qq = 0; qq < 4; qq++) {
    m[qq] = -1e30f; l[qq] = 0.f;
#pragma unroll
    for (int k = 0; k < 8; k++) o[qq][k] = v2f{0.f, 0.f};
  }

  for (int k0 = 0; k0 < nv; k0 += 128) {
    __syncthreads();
    // stage 128 gathered K/V rows cooperatively (zero-fill past nv).
    {
      const int quad = tid & 3;
      const int jr = tid >> 2;  // 0..127
      int j = k0 + jr;
      float4 kv = {0, 0, 0, 0}, vv = {0, 0, 0, 0};
      if (j < nv) {
        int kk = vidx[b * NT + j];
        size_t bse = ((size_t)bh * NT + kk) * NS + (quad << 2);
        kv = *(const float4*)(K + bse);
        vv = *(const float4*)(V + bse);
      }
      *(float4*)(Ks + jr * 16 + (quad << 2)) = kv;
      *(float4*)(Vs + jr * 16 + (quad << 2)) = vv;
    }
    __syncthreads();
    int jmax = nv - k0;
    if (jmax > 128) jmax = 128;
    // wave s handles tile rows r == s (mod 8): row = s + (g<<5) + (i<<3)
    for (int g = 0; g < 4; g++) {
      const int rb = s + (g << 5);
      if (rb >= jmax) break;  // wave-uniform
      float sc[4][4];
#pragma unroll
      for (int i = 0; i < 4; i++) {
        const float4* kr = (const float4*)(Ks + (rb + (i << 3)) * 16);
        const float4 k0v = kr[0], k1v = kr[1], k2v = kr[2], k3v = kr[3];
#pragma unroll
        for (int qq = 0; qq < 4; qq++)
          sc[qq][i] =
              dot16p(q[qq][0], q[qq][1], q[qq][2], q[qq][3], k0v, k1v, k2v, k3v);
      }
#pragma unroll
      for (int i = 0; i < 4; i++)
        if (rb + (i << 3) >= jmax) {
          sc[0][i] = -1e30f; sc[1][i] = -1e30f;
          sc[2][i] = -1e30f; sc[3][i] = -1e30f;
        }
      float p[4][4];
#pragma unroll
      for (int qq = 0; qq < 4; qq++) {
        float mb =
            fmaxf(fmaxf(sc[qq][0], sc[qq][1]), fmaxf(sc[qq][2], sc[qq][3]));
        if (mb > m[qq]) {
          float al = __expf(m[qq] - mb);
          v2f al2 = {al, al};
          l[qq] *= al;
#pragma unroll
          for (int k = 0; k < 8; k++) o[qq][k] *= al2;
          m[qq] = mb;
        }
        p[qq][0] = __expf(sc[qq][0] - m[qq]);
        p[qq][1] = __expf(sc[qq][1] - m[qq]);
        p[qq][2] = __expf(sc[qq][2] - m[qq]);
        p[qq][3] = __expf(sc[qq][3] - m[qq]);
        l[qq] += (p[qq][0] + p[qq][1]) + (p[qq][2] + p[qq][3]);
      }
#pragma unroll
      for (int i = 0; i < 4; i++) {
        const float4* vr = (const float4*)(Vs + (rb + (i << 3)) * 16);
        const float4 v0 = vr[0], v1 = vr[1], v2 = vr[2], v3 = vr[3];
#pragma unroll
        for (int qq = 0; qq < 4; qq++) {
          const v2f pq = {p[qq][i], p[qq][i]};
          o[qq][0] = pfma(pq, vlo(v0), o[qq][0]);
          o[qq][1] = pfma(pq, vhi(v0), o[qq][1]);
          o[qq][2] = pfma(pq, vlo(v1), o[qq][2]);
          o[qq][3] = pfma(pq, vhi(v1), o[qq][3]);
          o[qq][4] = pfma(pq, vlo(v2), o[qq][4]);
          o[qq][5] = pfma(pq, vhi(v2), o[qq][5]);
          o[qq][6] = pfma(pq, vlo(v3), o[qq][6]);
          o[qq][7] = pfma(pq, vhi(v3), o[qq][7]);
        }
      }
    }
  }

  // ---- epilogue: 4 phases (one per query slot), fully-parallel combine ----
  // om aliases Ks/Vs: [8 splits][64 lanes][20] (o[16], m, l, pad2)
  float* om = smem;
#pragma unroll
  for (int ph = 0; ph < 4; ph++) {
    __syncthreads();  // main-loop / previous-phase reads done
    {
      float* pa = om + (s * 64 + lane) * 20;
#pragma unroll
      for (int k = 0; k < 8; k++) *(v2f*)(pa + k * 2) = o[ph][k];
      pa[16] = m[ph];
      pa[17] = l[ph];
    }
    __syncthreads();
    {
      const int q8 = tid >> 3;   // 0..63: query within slot
      const int sub = tid & 7;   // 0..7: which v2f of the 16-float output
      const int cq = tbase + (ph << 6) + q8;
      if (cq < nv) {
        float ms[8], ls[8];
#pragma unroll
        for (int ss = 0; ss < 8; ss++) {
          const float* pp = om + (ss * 64 + q8) * 20;
          ms[ss] = pp[16];
          ls[ss] = pp[17];
        }
        float M = fmaxf(fmaxf(fmaxf(ms[0], ms[1]), fmaxf(ms[2], ms[3])),
                        fmaxf(fmaxf(ms[4], ms[5]), fmaxf(ms[6], ms[7])));
        float L = 0.f;
        v2f y = {0.f, 0.f};
#pragma unroll
        for (int ss = 0; ss < 8; ss++) {
          float f = __expf(ms[ss] - M);
          L = fmaf(f, ls[ss], L);
          v2f ov = *(const v2f*)(om + (ss * 64 + q8) * 20 + sub * 2);
          y = pfma(v2f{f, f}, ov, y);
        }
        const int tq = vidx[b * NT + cq];
        const float inv = (L > 0.f) ? (1.0f / L) : 0.f;
        y *= v2f{inv, inv};
        *(v2f*)(Y + ((size_t)b * NT + tq) * NE + h * NS + sub * 2) = y;
      }
    }
  }
}

// ---------------- Kernel C: out = Y @ Wu^T + bu --------------------------
// grid = B*T/16 = 512 blocks, 256 threads. 16 rows/block.
// Masked rows of Y are NOT written by the compacted attn kernel -> zero them
// here at Yt staging (mask select; also makes stale-workspace garbage safe).
__global__ __launch_bounds__(256) void proj_kernel(
    const float* __restrict__ Y, const int* __restrict__ masks,
    const float* __restrict__ Wu, const float* __restrict__ bu,
    float* __restrict__ out) {
  __shared__ __align__(16) float Wt[64 * WT_PITCH];  // 33792 B
  __shared__ __align__(16) float Yt[16 * 128];       // 8192 B
  const int tid = threadIdx.x;
  const int r0 = blockIdx.x * 16;
  const float4* yg = (const float4*)(Y + (size_t)r0 * 128);
  float4* yt4 = (float4*)Yt;
  {
    const float4 z = {0, 0, 0, 0};
    const int m0 = masks[r0 + (tid >> 5)];
    const int m1 = masks[r0 + 8 + (tid >> 5)];
    float4 v0 = yg[tid];
    float4 v1 = yg[tid + 256];
    yt4[tid] = m0 ? v0 : z;
    yt4[tid + 256] = m1 ? v1 : z;
  }
  const int c0 = (tid & 31) << 2;
  const int rg = (tid >> 5) & 3;
  const int eh = tid >> 7;  // 0 or 1
  float4 acc0 = {0, 0, 0, 0}, acc1 = {0, 0, 0, 0}, acc2 = {0, 0, 0, 0},
         acc3 = {0, 0, 0, 0};
  for (int e0 = 0; e0 < 128; e0 += 64) {
    __syncthreads();  // guards Yt staging (iter 0) and Wt reuse (iter 1)
#pragma unroll
    for (int p = 0; p < 8; p++) {
      int idx = tid + p * 256;
      int c = idx >> 4;
      int es = (idx & 15) << 2;
      float4 w = *(const float4*)(Wu + c * 128 + e0 + es);
      Wt[(es + 0) * WT_PITCH + c] = w.x;
      Wt[(es + 1) * WT_PITCH + c] = w.y;
      Wt[(es + 2) * WT_PITCH + c] = w.z;
      Wt[(es + 3) * WT_PITCH + c] = w.w;
    }
    __syncthreads();
    const int eb = eh << 5;  // this thread's e-half within the 64-chunk
    const float* y0 = Yt + (rg * 4 + 0) * 128 + e0 + eb;
    const float* y1 = Yt + (rg * 4 + 1) * 128 + e0 + eb;
    const float* y2 = Yt + (rg * 4 + 2) * 128 + e0 + eb;
    const float* y3 = Yt + (rg * 4 + 3) * 128 + e0 + eb;
#pragma unroll 4
    for (int e = 0; e < 32; e += 4) {
      const float* wb = Wt + (eb + e) * WT_PITCH + c0;
      float4 w0 = *(const float4*)(wb + 0 * WT_PITCH);
      float4 w1 = *(const float4*)(wb + 1 * WT_PITCH);
      float4 w2 = *(const float4*)(wb + 2 * WT_PITCH);
      float4 w3 = *(const float4*)(wb + 3 * WT_PITCH);
      float4 ya = *(const float4*)(y0 + e);
      float4 yb = *(const float4*)(y1 + e);
      float4 yc = *(const float4*)(y2 + e);
      float4 yd = *(const float4*)(y3 + e);
      fma4(acc0, ya.x, w0); fma4(acc0, ya.y, w1); fma4(acc0, ya.z, w2); fma4(acc0, ya.w, w3);
      fma4(acc1, yb.x, w0); fma4(acc1, yb.y, w1); fma4(acc1, yb.z, w2); fma4(acc1, yb.w, w3);
      fma4(acc2, yc.x, w0); fma4(acc2, yc.y, w1); fma4(acc2, yc.z, w2); fma4(acc2, yc.w, w3);
      fma4(acc3, yd.x, w0); fma4(acc3, yd.y, w1); fma4(acc3, yd.z, w2); fma4(acc3, yd.w, w3);
    }
  }
  // combine e-halves through LDS (Wt dead; pitch 20 to spread banks)
  __syncthreads();
  if (eh == 1) {
    float* p = Wt + (tid & 127) * 20;
    *(float4*)(p + 0) = acc0; *(float4*)(p + 4) = acc1;
    *(float4*)(p + 8) = acc2; *(float4*)(p + 12) = acc3;
  }
  __syncthreads();
  if (eh == 0) {
    const float* p = Wt + tid * 20;
    float4 b4 = *(const float4*)(bu + c0);
    float4 q0 = *(const float4*)(p + 0);
    float4 q1 = *(const float4*)(p + 4);
    float4 q2 = *(const float4*)(p + 8);
    float4 q3 = *(const float4*)(p + 12);
    acc0.x += q0.x + b4.x; acc0.y += q0.y + b4.y; acc0.z += q0.z + b4.z; acc0.w += q0.w + b4.w;
    acc1.x += q1.x + b4.x; acc1.y += q1.y + b4.y; acc1.z += q1.z + b4.z; acc1.w += q1.w + b4.w;
    acc2.x += q2.x + b4.x; acc2.y += q2.y + b4.y; acc2.z += q2.z + b4.z; acc2.w += q2.w + b4.w;
    acc3.x += q3.x + b4.x; acc3.y += q3.y + b4.y; acc3.z += q3.z + b4.z; acc3.w += q3.w + b4.w;
    *(float4*)(out + (size_t)(r0 + rg * 4 + 0) * 128 + c0) = acc0;
    *(float4*)(out + (size_t)(r0 + rg * 4 + 1) * 128 + c0) = acc1;
    *(float4*)(out + (size_t)(r0 + rg * 4 + 2) * 128 + c0) = acc2;
    *(float4*)(out + (size_t)(r0 + rg * 4 + 3) * 128 + c0) = acc3;
  }
}

extern "C" void kernel_launch(void* const* d_in, const int* in_sizes, int n_in,
                              void* d_out, int out_size, void* d_ws,
                              size_t ws_size, hipStream_t stream) {
  const float* x = (const float*)d_in[0];
  const int* masks = (const int*)d_in[1];
  const float* Wq = (const float*)d_in[2];
  const float* Wk = (const float*)d_in[3];
  const float* Wv = (const float*)d_in[4];
  const float* Wu = (const float*)d_in[5];
  const float* bu = (const float*)d_in[6];
  float* out = (float*)d_out;

  float* ws = (float*)d_ws;
  float* Q = ws + WS_Q;
  float* K = ws + WS_K;
  float* V = ws + WS_V;
  float* Y = ws + WS_Y;
  int* vidx = (int*)(ws + WS_VIDX);
  int* vcount = vidx + NB * NT;

  qkv_kernel<<<1024 + NB, 256, 0, stream>>>(x, masks, Wq, Wk, Wv, Q, K, V,
                                            vidx, vcount);
  // grid = 4 compacted-query tiles x 64 (b,h); tile-major for CU balance
  attn_kernel<<<4 * NB * NH, 512, 0, stream>>>(Q, K, V, vidx, vcount, Y);
  proj_kernel<<<NB * NT / 16, 256, 0, stream>>>(Y, masks, Wu, bu, out);
}